// Round 7
// baseline (165.049 us; speedup 1.0000x reference)
//
#include <hip/hip_runtime.h>

#define T_TOK   32768
#define HDIM    2048
#define NEXP    8
#define SEQ     8192
#define NBATCH  4
#define ALPHA   0.1f

#define BLOCK   512
#define TPB     64                 // tokens per block: 8 waves x 8
#define NBLK    (T_TOK / TPB)      // 512
#define BPB     (SEQ / TPB)        // 128 blocks per batch
#define H4      (HDIM / 4)         // 512 float4 per row
#define NJ2     (H4 / 32)          // 16 j-phases (32-lane H split)

// ---------------------------------------------------------------- main gate
// Wave = 2 groups of 32 lanes; each group owns 4 consecutive tokens (M=4).
// w staged in LDS (64 KB/block), read once per 4 tokens. x streamed with
// 2-phase register lookahead.
// __launch_bounds__(512,4): VGPR cap 128 -> 2 blocks/CU (16 waves). Round-6
// regression was cap-256 letting the allocator exceed 128 -> 1 block/CU.
// All array indices compile-time static (rule #20): round-5 regression was
// acc[runtime] demoting acc[4][8] to scratch.
// Aux partials go to a PRIVATE per-block slot ws[block*16..] (no pre-zero
// needed -> no init kernel; no global atomics).
__global__ __launch_bounds__(BLOCK, 4) void gate_kernel(
    const float* __restrict__ x,       // [T_TOK, HDIM]
    const float* __restrict__ w,       // [NEXP, HDIM]
    float* __restrict__ out_idx,       // [T_TOK, 2] float-encoded
    float* __restrict__ out_wt,        // [T_TOK, 2]
    float* __restrict__ ws)            // [NBLK*16] per-block partials
{
    __shared__ float4 wlds[NEXP * H4]; // 64 KB
    __shared__ float sacc[16];

    const int tid  = threadIdx.x;
    const int wid  = tid >> 6;
    const int lane = tid & 63;
    const int grp  = lane >> 5;        // 2 groups per wave
    const int col  = lane & 31;        // 32-lane H split

    // stage weights: 4096 float4s, 8 per thread, coalesced
    const float4* w4 = (const float4*)w;
    #pragma unroll
    for (int i = 0; i < 8; ++i)
        wlds[tid + i * BLOCK] = w4[tid + i * BLOCK];
    if (tid < 16) sacc[tid] = 0.0f;
    __syncthreads();

    const int tok0 = blockIdx.x * TPB + wid * 8 + grp * 4;   // group's 1st token

    const float4* xp0 = (const float4*)x + (size_t)tok0 * H4 + col;
    const float4* xp1 = xp0 + H4;
    const float4* xp2 = xp0 + 2 * H4;
    const float4* xp3 = xp0 + 3 * H4;

    float acc[4][NEXP];
    #pragma unroll
    for (int m = 0; m < 4; ++m)
        #pragma unroll
        for (int e = 0; e < NEXP; ++e) acc[m][e] = 0.0f;

    float4 xb0[4], xb1[4];             // x slots for even/odd phases (4 tokens)
    float4 wA[4], wB[4];               // expert halves for current phase (LDS)

#define LOADX(DST, J)                          \
    DST[0] = xp0[(J) * 32];                    \
    DST[1] = xp1[(J) * 32];                    \
    DST[2] = xp2[(J) * 32];                    \
    DST[3] = xp3[(J) * 32];

    // prologue
    LOADX(xb0, 0)
    LOADX(xb1, 1)
    #pragma unroll
    for (int e = 0; e < 4; ++e) wA[e] = wlds[e * H4 + col];
    #pragma unroll
    for (int e = 0; e < 4; ++e) wB[e] = wlds[(e + 4) * H4 + col];

#define FMA4(ACC, XV, WV)                      \
    ACC = fmaf((XV).x, (WV).x, ACC);           \
    ACC = fmaf((XV).y, (WV).y, ACC);           \
    ACC = fmaf((XV).z, (WV).z, ACC);           \
    ACC = fmaf((XV).w, (WV).w, ACC);

#define COMPUTE_HALF(XB, WH, EBASE)            \
    _Pragma("unroll")                          \
    for (int e = 0; e < 4; ++e) {              \
        const float4 wv = WH[e];               \
        FMA4(acc[0][(EBASE) + e], XB[0], wv);  \
        FMA4(acc[1][(EBASE) + e], XB[1], wv);  \
        FMA4(acc[2][(EBASE) + e], XB[2], wv);  \
        FMA4(acc[3][(EBASE) + e], XB[3], wv);  \
    }

    #pragma unroll 1
    for (int jj = 0; jj < NJ2 - 2; jj += 2) {
        // ---- phase jj (even slot)
        COMPUTE_HALF(xb0, wA, 0)
        #pragma unroll
        for (int e = 0; e < 4; ++e) wA[e] = wlds[e * H4 + (jj + 1) * 32 + col];
        COMPUTE_HALF(xb0, wB, 4)
        #pragma unroll
        for (int e = 0; e < 4; ++e) wB[e] = wlds[(e + 4) * H4 + (jj + 1) * 32 + col];
        LOADX(xb0, jj + 2)

        // ---- phase jj+1 (odd slot)
        COMPUTE_HALF(xb1, wA, 0)
        #pragma unroll
        for (int e = 0; e < 4; ++e) wA[e] = wlds[e * H4 + (jj + 2) * 32 + col];
        COMPUTE_HALF(xb1, wB, 4)
        #pragma unroll
        for (int e = 0; e < 4; ++e) wB[e] = wlds[(e + 4) * H4 + (jj + 2) * 32 + col];
        LOADX(xb1, jj + 3)
    }

    // ---- peeled tail: phases NJ2-2, NJ2-1
    {
        COMPUTE_HALF(xb0, wA, 0)
        #pragma unroll
        for (int e = 0; e < 4; ++e) wA[e] = wlds[e * H4 + (NJ2 - 1) * 32 + col];
        COMPUTE_HALF(xb0, wB, 4)
        #pragma unroll
        for (int e = 0; e < 4; ++e) wB[e] = wlds[(e + 4) * H4 + (NJ2 - 1) * 32 + col];
        COMPUTE_HALF(xb1, wA, 0)
        COMPUTE_HALF(xb1, wB, 4)
    }

    // reduce partials across the 32-lane group (2 groups in parallel)
    #pragma unroll
    for (int m = 0; m < 4; ++m)
        #pragma unroll
        for (int e = 0; e < NEXP; ++e) {
            float v = acc[m][e];
            v += __shfl_xor(v, 1);
            v += __shfl_xor(v, 2);
            v += __shfl_xor(v, 4);
            v += __shfl_xor(v, 8);
            v += __shfl_xor(v, 16);
            acc[m][e] = v;             // all 32 lanes hold all 4 tokens' logits
        }

    // lane-local epilogue: lane col handles token (col & 3), selected via a
    // STATIC cndmask tree (no runtime array index -> no scratch).
    const bool selLo = (col & 1) != 0;
    const bool selHi = (col & 2) != 0;
    float l[NEXP];
    #pragma unroll
    for (int e = 0; e < NEXP; ++e) {
        const float v01 = selLo ? acc[1][e] : acc[0][e];
        const float v23 = selLo ? acc[3][e] : acc[2][e];
        l[e] = selHi ? v23 : v01;
    }

    float mx = l[0];
    #pragma unroll
    for (int e = 1; e < NEXP; ++e) mx = fmaxf(mx, l[e]);

    float p[NEXP];
    float psum = 0.0f;
    #pragma unroll
    for (int e = 0; e < NEXP; ++e) { p[e] = __expf(l[e] - mx); psum += p[e]; }
    const float inv = 1.0f / psum;
    float s[NEXP];
    #pragma unroll
    for (int e = 0; e < NEXP; ++e) s[e] = p[e] * inv;

    float s1 = s[0]; int i1 = 0;       // strict > keeps lowest index (lax.top_k)
    #pragma unroll
    for (int e = 1; e < NEXP; ++e) if (s[e] > s1) { s1 = s[e]; i1 = e; }
    float s2 = -1.0f; int i2 = 0;
    #pragma unroll
    for (int e = 0; e < NEXP; ++e) if (e != i1 && s[e] > s2) { s2 = s[e]; i2 = e; }

    const float wsum = s1 + s2 + 1e-20f;
    const float w1 = s1 / wsum;
    const float w2 = s2 / wsum;

    if (col < 4) {
        const int tok = tok0 + (col & 3);
        ((float2*)out_idx)[tok] = make_float2((float)i1, (float)i2);
        ((float2*)out_wt)[tok]  = make_float2(w1, w2);
    }

    // aux partials: lanes col 0..3 of each group carry their token's stats
    const float sel = (col < 4) ? 1.0f : 0.0f;
    #pragma unroll
    for (int e = 0; e < NEXP; ++e) {
        float pi = s[e] * sel;
        float ce = (((i1 == e) ? 1.0f : 0.0f) + ((i2 == e) ? 1.0f : 0.0f)) * sel;
        pi += __shfl_xor(pi, 1);  ce += __shfl_xor(ce, 1);   // tokens 0+1, 2+3
        pi += __shfl_xor(pi, 2);  ce += __shfl_xor(ce, 2);   // all 4 tokens
        pi += __shfl_xor(pi, 32); ce += __shfl_xor(ce, 32);  // both groups
        if (lane == 0) {
            atomicAdd(&sacc[e], pi);
            atomicAdd(&sacc[8 + e], ce);
        }
    }
    __syncthreads();
    // private per-block slot: fully overwritten every launch (no init needed)
    if (tid < 16)
        ws[blockIdx.x * 16 + tid] = sacc[tid];
}

// ---------------------------------------------------------------- finalize
// Reduce 512 blocks x 16 partials (32 KB, L2-resident) and emit aux loss.
__global__ __launch_bounds__(256) void finalize_kernel(const float* __restrict__ ws,
                                                       float* __restrict__ out_aux) {
    __shared__ float sfin[NBATCH][16];
    const int t    = threadIdx.x;
    const int b    = t >> 6;          // one wave per batch
    const int lane = t & 63;
    const int slot = lane & 15;

    float v = 0.0f;
    for (int j = lane >> 4; j < BPB; j += 4)          // 32 blocks per lane
        v += ws[(b * BPB + j) * 16 + slot];
    v += __shfl_xor(v, 16);
    v += __shfl_xor(v, 32);
    if (lane < 16) sfin[b][slot] = v;
    __syncthreads();

    if (t == 0) {
        float aux = 0.0f;
        #pragma unroll
        for (int bb = 0; bb < NBATCH; ++bb) {
            float dot = 0.0f;
            #pragma unroll
            for (int e = 0; e < NEXP; ++e) {
                const float pi = sfin[bb][e] / (float)SEQ;
                const float ce = sfin[bb][8 + e] * ((float)NEXP / (float)(SEQ * 2));
                dot = fmaf(ce, pi, dot);
            }
            aux += dot;
        }
        out_aux[0] = aux * (1.0f / NBATCH) * ALPHA;
    }
}

// ---------------------------------------------------------------- launch
extern "C" void kernel_launch(void* const* d_in, const int* in_sizes, int n_in,
                              void* d_out, int out_size, void* d_ws, size_t ws_size,
                              hipStream_t stream) {
    const float* x = (const float*)d_in[0];   // hidden_states [4,8192,2048]
    const float* w = (const float*)d_in[1];   // weight [8,2048]

    float* out     = (float*)d_out;
    float* out_idx = out;                  // [32768,2]
    float* out_wt  = out + 2 * T_TOK;      // [32768,2]
    float* out_aux = out + 4 * T_TOK;      // [1]
    float* ws      = (float*)d_ws;         // [NBLK*16]

    gate_kernel<<<NBLK, BLOCK, 0, stream>>>(x, w, out_idx, out_wt, ws);
    finalize_kernel<<<1, 256, 0, stream>>>(ws, out_aux);
}

// Round 8
// 70.970 us; speedup vs baseline: 2.3256x; 2.3256x over previous
//
#include <hip/hip_runtime.h>

#define T_TOK   32768
#define HDIM    2048
#define NEXP    8
#define SEQ     8192
#define NBATCH  4
#define ALPHA   0.1f

#define BLOCK   512
#define TPB     64                 // tokens per block: 8 waves x 8
#define NBLK    (T_TOK / TPB)      // 512
#define BPB     (SEQ / TPB)        // 128 blocks per batch
#define H4      (HDIM / 4)         // 512 float4 per row
#define NJ      (H4 / 16)          // 32 j-phases (16-lane H split)

// ---------------------------------------------------------------- main gate
// Round-4 shape (fastest measured): wave = 4 groups of 16 lanes, each group
// owns 2 consecutive tokens (M=2). w staged in LDS (64 KB/block); x streamed
// with 2-phase register lookahead.
// __launch_bounds__(512,2): on this hipcc the 2nd arg acts like CUDA's
// minBlocks/CU -> 2 blocks x 8 waves / 4 SIMD = 4 waves/EU -> VGPR cap 128.
// ((512,4) gave cap 64 -> observed VGPR=64 + 130 MB scratch FETCH in r5/r7.)
// All register-array indices are compile-time static (rule #20).
// Aux partials go to a PRIVATE per-block ws slot (fully overwritten every
// launch -> no init kernel, poison-safe, no global atomics).
__global__ __launch_bounds__(BLOCK, 2) void gate_kernel(
    const float* __restrict__ x,       // [T_TOK, HDIM]
    const float* __restrict__ w,       // [NEXP, HDIM]
    float* __restrict__ out_idx,       // [T_TOK, 2] float-encoded
    float* __restrict__ out_wt,        // [T_TOK, 2]
    float* __restrict__ ws)            // [NBLK*16] per-block partials
{
    __shared__ float4 wlds[NEXP * H4]; // 64 KB
    __shared__ float sacc[16];

    const int tid  = threadIdx.x;
    const int wid  = tid >> 6;
    const int lane = tid & 63;
    const int grp  = lane >> 4;        // 4 groups per wave
    const int col  = lane & 15;        // 16-lane H split

    // stage weights: 4096 float4s, 8 per thread, coalesced
    const float4* w4 = (const float4*)w;
    #pragma unroll
    for (int i = 0; i < 8; ++i)
        wlds[tid + i * BLOCK] = w4[tid + i * BLOCK];
    if (tid < 16) sacc[tid] = 0.0f;
    __syncthreads();

    const int tok0 = blockIdx.x * TPB + wid * 8 + grp * 2;   // group's 1st token

    const float4* xp0 = (const float4*)x + (size_t)tok0 * H4 + col;
    const float4* xp1 = xp0 + H4;                            // 2nd token

    float acc[2][NEXP];
    #pragma unroll
    for (int t = 0; t < 2; ++t)
        #pragma unroll
        for (int e = 0; e < NEXP; ++e) acc[t][e] = 0.0f;

    float4 xb0[2], xb1[2];             // x slots for even/odd phases (2 tokens)
    float4 wA[4], wB[4];               // expert halves for current phase (LDS)

    // prologue
    xb0[0] = xp0[0];        xb0[1] = xp1[0];
    xb1[0] = xp0[16];       xb1[1] = xp1[16];
    #pragma unroll
    for (int e = 0; e < 4; ++e) wA[e] = wlds[e * H4 + col];
    #pragma unroll
    for (int e = 0; e < 4; ++e) wB[e] = wlds[(e + 4) * H4 + col];

#define FMA4(ACC, XV, WV)                      \
    ACC = fmaf((XV).x, (WV).x, ACC);           \
    ACC = fmaf((XV).y, (WV).y, ACC);           \
    ACC = fmaf((XV).z, (WV).z, ACC);           \
    ACC = fmaf((XV).w, (WV).w, ACC);

#define COMPUTE_HALF(XB, WH, EBASE)            \
    _Pragma("unroll")                          \
    for (int e = 0; e < 4; ++e) {              \
        const float4 wv = WH[e];               \
        FMA4(acc[0][(EBASE) + e], XB[0], wv);  \
        FMA4(acc[1][(EBASE) + e], XB[1], wv);  \
    }

    #pragma unroll 1
    for (int jj = 0; jj < NJ - 2; jj += 2) {
        // ---- phase jj (even slot)
        COMPUTE_HALF(xb0, wA, 0)
        #pragma unroll
        for (int e = 0; e < 4; ++e) wA[e] = wlds[e * H4 + (jj + 1) * 16 + col];
        COMPUTE_HALF(xb0, wB, 4)
        #pragma unroll
        for (int e = 0; e < 4; ++e) wB[e] = wlds[(e + 4) * H4 + (jj + 1) * 16 + col];
        xb0[0] = xp0[(jj + 2) * 16];
        xb0[1] = xp1[(jj + 2) * 16];

        // ---- phase jj+1 (odd slot)
        COMPUTE_HALF(xb1, wA, 0)
        #pragma unroll
        for (int e = 0; e < 4; ++e) wA[e] = wlds[e * H4 + (jj + 2) * 16 + col];
        COMPUTE_HALF(xb1, wB, 4)
        #pragma unroll
        for (int e = 0; e < 4; ++e) wB[e] = wlds[(e + 4) * H4 + (jj + 2) * 16 + col];
        xb1[0] = xp0[(jj + 3) * 16];
        xb1[1] = xp1[(jj + 3) * 16];
    }

    // ---- peeled tail: phases NJ-2, NJ-1
    {
        COMPUTE_HALF(xb0, wA, 0)
        #pragma unroll
        for (int e = 0; e < 4; ++e) wA[e] = wlds[e * H4 + (NJ - 1) * 16 + col];
        COMPUTE_HALF(xb0, wB, 4)
        #pragma unroll
        for (int e = 0; e < 4; ++e) wB[e] = wlds[(e + 4) * H4 + (NJ - 1) * 16 + col];
        COMPUTE_HALF(xb1, wA, 0)
        COMPUTE_HALF(xb1, wB, 4)
    }

    // reduce partials across the 16-lane group (4 groups in parallel)
    #pragma unroll
    for (int t = 0; t < 2; ++t)
        #pragma unroll
        for (int e = 0; e < NEXP; ++e) {
            float v = acc[t][e];
            v += __shfl_xor(v, 1);
            v += __shfl_xor(v, 2);
            v += __shfl_xor(v, 4);
            v += __shfl_xor(v, 8);
            acc[t][e] = v;             // all 16 lanes hold both tokens' logits
        }

    // lane-local epilogue: lane col handles token (col & 1) via static select
    const bool selLo = (col & 1) != 0;
    float l[NEXP];
    #pragma unroll
    for (int e = 0; e < NEXP; ++e)
        l[e] = selLo ? acc[1][e] : acc[0][e];

    float mx = l[0];
    #pragma unroll
    for (int e = 1; e < NEXP; ++e) mx = fmaxf(mx, l[e]);

    float p[NEXP];
    float psum = 0.0f;
    #pragma unroll
    for (int e = 0; e < NEXP; ++e) { p[e] = __expf(l[e] - mx); psum += p[e]; }
    const float inv = 1.0f / psum;
    float s[NEXP];
    #pragma unroll
    for (int e = 0; e < NEXP; ++e) s[e] = p[e] * inv;

    float s1 = s[0]; int i1 = 0;       // strict > keeps lowest index (lax.top_k)
    #pragma unroll
    for (int e = 1; e < NEXP; ++e) if (s[e] > s1) { s1 = s[e]; i1 = e; }
    float s2 = -1.0f; int i2 = 0;
    #pragma unroll
    for (int e = 0; e < NEXP; ++e) if (e != i1 && s[e] > s2) { s2 = s[e]; i2 = e; }

    const float wsum = s1 + s2 + 1e-20f;
    const float w1 = s1 / wsum;
    const float w2 = s2 / wsum;

    if (col < 2) {
        const int tok = tok0 + (col & 1);
        ((float2*)out_idx)[tok] = make_float2((float)i1, (float)i2);
        ((float2*)out_wt)[tok]  = make_float2(w1, w2);
    }

    // aux partials: lanes col 0,1 of each group carry their token's stats
    const float sel = (col < 2) ? 1.0f : 0.0f;
    #pragma unroll
    for (int e = 0; e < NEXP; ++e) {
        float pi = s[e] * sel;
        float ce = (((i1 == e) ? 1.0f : 0.0f) + ((i2 == e) ? 1.0f : 0.0f)) * sel;
        pi += __shfl_xor(pi, 1);  ce += __shfl_xor(ce, 1);   // token pair
        pi += __shfl_xor(pi, 16); ce += __shfl_xor(ce, 16);  // groups
        pi += __shfl_xor(pi, 32); ce += __shfl_xor(ce, 32);
        if (lane == 0) {
            atomicAdd(&sacc[e], pi);
            atomicAdd(&sacc[8 + e], ce);
        }
    }
    __syncthreads();
    // private per-block slot: fully overwritten every launch (no init needed)
    if (tid < 16)
        ws[blockIdx.x * 16 + tid] = sacc[tid];
}

// ---------------------------------------------------------------- finalize
// Reduce 512 blocks x 16 partials (32 KB, L2-resident) and emit aux loss.
__global__ __launch_bounds__(256) void finalize_kernel(const float* __restrict__ ws,
                                                       float* __restrict__ out_aux) {
    __shared__ float sfin[NBATCH][16];
    const int t    = threadIdx.x;
    const int b    = t >> 6;          // one wave per batch
    const int lane = t & 63;
    const int slot = lane & 15;

    float v = 0.0f;
    for (int j = lane >> 4; j < BPB; j += 4)          // 32 blocks per lane
        v += ws[(b * BPB + j) * 16 + slot];
    v += __shfl_xor(v, 16);
    v += __shfl_xor(v, 32);
    if (lane < 16) sfin[b][slot] = v;
    __syncthreads();

    if (t == 0) {
        float aux = 0.0f;
        #pragma unroll
        for (int bb = 0; bb < NBATCH; ++bb) {
            float dot = 0.0f;
            #pragma unroll
            for (int e = 0; e < NEXP; ++e) {
                const float pi = sfin[bb][e] / (float)SEQ;
                const float ce = sfin[bb][8 + e] * ((float)NEXP / (float)(SEQ * 2));
                dot = fmaf(ce, pi, dot);
            }
            aux += dot;
        }
        out_aux[0] = aux * (1.0f / NBATCH) * ALPHA;
    }
}

// ---------------------------------------------------------------- launch
extern "C" void kernel_launch(void* const* d_in, const int* in_sizes, int n_in,
                              void* d_out, int out_size, void* d_ws, size_t ws_size,
                              hipStream_t stream) {
    const float* x = (const float*)d_in[0];   // hidden_states [4,8192,2048]
    const float* w = (const float*)d_in[1];   // weight [8,2048]

    float* out     = (float*)d_out;
    float* out_idx = out;                  // [32768,2]
    float* out_wt  = out + 2 * T_TOK;      // [32768,2]
    float* out_aux = out + 4 * T_TOK;      // [1]
    float* ws      = (float*)d_ws;         // [NBLK*16]

    gate_kernel<<<NBLK, BLOCK, 0, stream>>>(x, w, out_idx, out_wt, ws);
    finalize_kernel<<<1, 256, 0, stream>>>(ws, out_aux);
}

// Round 9
// 65.198 us; speedup vs baseline: 2.5315x; 1.0885x over previous
//
#include <hip/hip_runtime.h>

#define T_TOK   32768
#define HDIM    2048
#define NEXP    8
#define SEQ     8192
#define NBATCH  4
#define ALPHA   0.1f

#define BLOCK   512
#define TPB     64                 // tokens per block: 8 waves x 8
#define NBLK    (T_TOK / TPB)      // 512
#define BPB     (SEQ / TPB)        // 128 blocks per batch
#define H4      (HDIM / 4)         // 512 float4 per row
#define NJ      (H4 / 16)          // 32 j-phases (16-lane H split)

// ---------------------------------------------------------------- main gate
// M=2 shape (fastest measured, r4): wave = 4 groups of 16 lanes, each group
// owns 2 consecutive tokens. w staged in LDS (64 KB/block); x streamed with
// 2-phase register lookahead.
// __launch_bounds__(512,4): 2nd arg = min WAVES PER EU -> VGPR cap 128.
//   (512,2) lets the allocator exceed 128 -> 1 block/CU (r6/r8 regressions).
//   M=4 body demand ~136 > 128 -> spill cascade (r5/r7). M=2 demand ~95 fits.
// All register-array indices compile-time static (rule #20).
// Aux partials -> PRIVATE per-block ws slot (fully overwritten every launch:
// no init kernel, poison-safe, no global atomics).
__global__ __launch_bounds__(BLOCK, 4) void gate_kernel(
    const float* __restrict__ x,       // [T_TOK, HDIM]
    const float* __restrict__ w,       // [NEXP, HDIM]
    float* __restrict__ out_idx,       // [T_TOK, 2] float-encoded
    float* __restrict__ out_wt,        // [T_TOK, 2]
    float* __restrict__ ws)            // [NBLK*16] per-block partials
{
    __shared__ float4 wlds[NEXP * H4]; // 64 KB
    __shared__ float sacc[16];

    const int tid  = threadIdx.x;
    const int wid  = tid >> 6;
    const int lane = tid & 63;
    const int grp  = lane >> 4;        // 4 groups per wave
    const int col  = lane & 15;        // 16-lane H split

    // stage weights: 4096 float4s, 8 per thread, coalesced
    const float4* w4 = (const float4*)w;
    #pragma unroll
    for (int i = 0; i < 8; ++i)
        wlds[tid + i * BLOCK] = w4[tid + i * BLOCK];
    if (tid < 16) sacc[tid] = 0.0f;
    __syncthreads();

    const int tok0 = blockIdx.x * TPB + wid * 8 + grp * 2;   // group's 1st token

    const float4* xp0 = (const float4*)x + (size_t)tok0 * H4 + col;
    const float4* xp1 = xp0 + H4;                            // 2nd token

    float acc[2][NEXP];
    #pragma unroll
    for (int t = 0; t < 2; ++t)
        #pragma unroll
        for (int e = 0; e < NEXP; ++e) acc[t][e] = 0.0f;

    float4 xb0[2], xb1[2];             // x slots for even/odd phases (2 tokens)
    float4 wA[4], wB[4];               // expert halves for current phase (LDS)

    // prologue
    xb0[0] = xp0[0];        xb0[1] = xp1[0];
    xb1[0] = xp0[16];       xb1[1] = xp1[16];
    #pragma unroll
    for (int e = 0; e < 4; ++e) wA[e] = wlds[e * H4 + col];
    #pragma unroll
    for (int e = 0; e < 4; ++e) wB[e] = wlds[(e + 4) * H4 + col];

#define FMA4(ACC, XV, WV)                      \
    ACC = fmaf((XV).x, (WV).x, ACC);           \
    ACC = fmaf((XV).y, (WV).y, ACC);           \
    ACC = fmaf((XV).z, (WV).z, ACC);           \
    ACC = fmaf((XV).w, (WV).w, ACC);

#define COMPUTE_HALF(XB, WH, EBASE)            \
    _Pragma("unroll")                          \
    for (int e = 0; e < 4; ++e) {              \
        const float4 wv = WH[e];               \
        FMA4(acc[0][(EBASE) + e], XB[0], wv);  \
        FMA4(acc[1][(EBASE) + e], XB[1], wv);  \
    }

    #pragma unroll 1
    for (int jj = 0; jj < NJ - 2; jj += 2) {
        // ---- phase jj (even slot): consume xb0, then refill xb0 for jj+2
        COMPUTE_HALF(xb0, wA, 0)
        COMPUTE_HALF(xb0, wB, 4)
        xb0[0] = xp0[(jj + 2) * 16];           // HBM loads first (~900 cy cover)
        xb0[1] = xp1[(jj + 2) * 16];
        #pragma unroll
        for (int e = 0; e < 4; ++e) wA[e] = wlds[e * H4 + (jj + 1) * 16 + col];
        #pragma unroll
        for (int e = 0; e < 4; ++e) wB[e] = wlds[(e + 4) * H4 + (jj + 1) * 16 + col];

        // ---- phase jj+1 (odd slot)
        COMPUTE_HALF(xb1, wA, 0)
        COMPUTE_HALF(xb1, wB, 4)
        xb1[0] = xp0[(jj + 3) * 16];
        xb1[1] = xp1[(jj + 3) * 16];
        #pragma unroll
        for (int e = 0; e < 4; ++e) wA[e] = wlds[e * H4 + (jj + 2) * 16 + col];
        #pragma unroll
        for (int e = 0; e < 4; ++e) wB[e] = wlds[(e + 4) * H4 + (jj + 2) * 16 + col];
    }

    // ---- peeled tail: phases NJ-2, NJ-1
    {
        COMPUTE_HALF(xb0, wA, 0)
        COMPUTE_HALF(xb0, wB, 4)
        #pragma unroll
        for (int e = 0; e < 4; ++e) wA[e] = wlds[e * H4 + (NJ - 1) * 16 + col];
        #pragma unroll
        for (int e = 0; e < 4; ++e) wB[e] = wlds[(e + 4) * H4 + (NJ - 1) * 16 + col];
        COMPUTE_HALF(xb1, wA, 0)
        COMPUTE_HALF(xb1, wB, 4)
    }

    // reduce partials across the 16-lane group (4 groups in parallel)
    #pragma unroll
    for (int t = 0; t < 2; ++t)
        #pragma unroll
        for (int e = 0; e < NEXP; ++e) {
            float v = acc[t][e];
            v += __shfl_xor(v, 1);
            v += __shfl_xor(v, 2);
            v += __shfl_xor(v, 4);
            v += __shfl_xor(v, 8);
            acc[t][e] = v;             // all 16 lanes hold both tokens' logits
        }

    // lane-local epilogue: lane col handles token (col & 1) via static select
    const bool selLo = (col & 1) != 0;
    float l[NEXP];
    #pragma unroll
    for (int e = 0; e < NEXP; ++e)
        l[e] = selLo ? acc[1][e] : acc[0][e];

    float mx = l[0];
    #pragma unroll
    for (int e = 1; e < NEXP; ++e) mx = fmaxf(mx, l[e]);

    float p[NEXP];
    float psum = 0.0f;
    #pragma unroll
    for (int e = 0; e < NEXP; ++e) { p[e] = __expf(l[e] - mx); psum += p[e]; }
    const float inv = 1.0f / psum;
    float s[NEXP];
    #pragma unroll
    for (int e = 0; e < NEXP; ++e) s[e] = p[e] * inv;

    float s1 = s[0]; int i1 = 0;       // strict > keeps lowest index (lax.top_k)
    #pragma unroll
    for (int e = 1; e < NEXP; ++e) if (s[e] > s1) { s1 = s[e]; i1 = e; }
    float s2 = -1.0f; int i2 = 0;
    #pragma unroll
    for (int e = 0; e < NEXP; ++e) if (e != i1 && s[e] > s2) { s2 = s[e]; i2 = e; }

    const float wsum = s1 + s2 + 1e-20f;
    const float w1 = s1 / wsum;
    const float w2 = s2 / wsum;

    if (col < 2) {
        const int tok = tok0 + (col & 1);
        ((float2*)out_idx)[tok] = make_float2((float)i1, (float)i2);
        ((float2*)out_wt)[tok]  = make_float2(w1, w2);
    }

    // aux partials: lanes col 0,1 of each group carry their token's stats
    const float sel = (col < 2) ? 1.0f : 0.0f;
    #pragma unroll
    for (int e = 0; e < NEXP; ++e) {
        float pi = s[e] * sel;
        float ce = (((i1 == e) ? 1.0f : 0.0f) + ((i2 == e) ? 1.0f : 0.0f)) * sel;
        pi += __shfl_xor(pi, 1);  ce += __shfl_xor(ce, 1);   // token pair
        pi += __shfl_xor(pi, 16); ce += __shfl_xor(ce, 16);  // groups
        pi += __shfl_xor(pi, 32); ce += __shfl_xor(ce, 32);
        if (lane == 0) {
            atomicAdd(&sacc[e], pi);
            atomicAdd(&sacc[8 + e], ce);
        }
    }
    __syncthreads();
    // private per-block slot: fully overwritten every launch (no init needed)
    if (tid < 16)
        ws[blockIdx.x * 16 + tid] = sacc[tid];
}

// ---------------------------------------------------------------- finalize
// Reduce 512 blocks x 16 partials (32 KB, L2-resident) and emit aux loss.
__global__ __launch_bounds__(256) void finalize_kernel(const float* __restrict__ ws,
                                                       float* __restrict__ out_aux) {
    __shared__ float sfin[NBATCH][16];
    const int t    = threadIdx.x;
    const int b    = t >> 6;          // one wave per batch
    const int lane = t & 63;
    const int slot = lane & 15;

    float v = 0.0f;
    for (int j = lane >> 4; j < BPB; j += 4)          // 32 blocks per lane
        v += ws[(b * BPB + j) * 16 + slot];
    v += __shfl_xor(v, 16);
    v += __shfl_xor(v, 32);
    if (lane < 16) sfin[b][slot] = v;
    __syncthreads();

    if (t == 0) {
        float aux = 0.0f;
        #pragma unroll
        for (int bb = 0; bb < NBATCH; ++bb) {
            float dot = 0.0f;
            #pragma unroll
            for (int e = 0; e < NEXP; ++e) {
                const float pi = sfin[bb][e] / (float)SEQ;
                const float ce = sfin[bb][8 + e] * ((float)NEXP / (float)(SEQ * 2));
                dot = fmaf(ce, pi, dot);
            }
            aux += dot;
        }
        out_aux[0] = aux * (1.0f / NBATCH) * ALPHA;
    }
}

// ---------------------------------------------------------------- launch
extern "C" void kernel_launch(void* const* d_in, const int* in_sizes, int n_in,
                              void* d_out, int out_size, void* d_ws, size_t ws_size,
                              hipStream_t stream) {
    const float* x = (const float*)d_in[0];   // hidden_states [4,8192,2048]
    const float* w = (const float*)d_in[1];   // weight [8,2048]

    float* out     = (float*)d_out;
    float* out_idx = out;                  // [32768,2]
    float* out_wt  = out + 2 * T_TOK;      // [32768,2]
    float* out_aux = out + 4 * T_TOK;      // [1]
    float* ws      = (float*)d_ws;         // [NBLK*16]

    gate_kernel<<<NBLK, BLOCK, 0, stream>>>(x, w, out_idx, out_wt, ws);
    finalize_kernel<<<1, 256, 0, stream>>>(ws, out_aux);
}